// Round 1
// baseline (1072.107 us; speedup 1.0000x reference)
//
#include <hip/hip_runtime.h>

#define N_NODES 100000
#define N_EDGES 1600000
#define D 64

// ---------------------------------------------------------------------------
// Degree count: cnt[dst[e]] += 1  (float, to match reference arithmetic)
// ---------------------------------------------------------------------------
__global__ __launch_bounds__(256) void count_kernel(const int* __restrict__ dst,
                                                    float* __restrict__ cnt) {
    int e = blockIdx.x * blockDim.x + threadIdx.x;
    if (e < N_EDGES) atomicAdd(&cnt[dst[e]], 1.0f);
}

// ---------------------------------------------------------------------------
// Scatter-sum: sum[dst[e]][d] += feat[src[e]][d]
// Thread t -> edge t/64, dim t%64. 64 consecutive threads read one source row
// (coalesced) and atomically add one destination row (coalesced).
// ---------------------------------------------------------------------------
__global__ __launch_bounds__(256) void scatter_kernel(const int* __restrict__ src,
                                                      const int* __restrict__ dst,
                                                      const float* __restrict__ feat,
                                                      float* __restrict__ sum) {
    long long t = (long long)blockIdx.x * blockDim.x + threadIdx.x;
    if (t >= (long long)N_EDGES * D) return;
    int e = (int)(t >> 6);
    int d = (int)(t & 63);
    float v = feat[(long long)src[e] * D + d];
    atomicAdd(&sum[(long long)dst[e] * D + d], v);
}

// ---------------------------------------------------------------------------
// Per-node SAGE layer: out = [relu](mean @ w_l^T + b_l + x @ w_r^T)
// Block = 256 threads = 4 nodes x 64 output dims.
// Weights staged transposed in LDS with stride 65: for fixed k, the 64 output
// lanes read consecutive addresses (2-way bank aliasing = free on gfx950).
// Node inputs read from LDS at wave-uniform addresses (broadcast = free).
// ---------------------------------------------------------------------------
__global__ __launch_bounds__(256) void layer_kernel(
    const float* __restrict__ sum, const float* __restrict__ cnt,
    const float* __restrict__ xin,
    const float* __restrict__ w_l, const float* __restrict__ b_l,
    const float* __restrict__ w_r,
    float* __restrict__ out, int apply_relu)
{
    __shared__ float wl_t[D * 65];
    __shared__ float wr_t[D * 65];
    __shared__ float bias[D];
    __shared__ float mean_s[4][D];
    __shared__ float x_s[4][D];

    int tid = threadIdx.x;
    // Stage transposed weights: w[o][k] -> w_t[k*65 + o]. Write addresses for
    // consecutive tids differ by 65 -> conflict-free.
    for (int i = tid; i < D * D; i += 256) {
        int o = i / D;
        int k = i % D;
        wl_t[k * 65 + o] = w_l[i];
        wr_t[k * 65 + o] = w_r[i];
    }
    if (tid < D) bias[tid] = b_l[tid];

    int ln = tid >> 6;       // local node 0..3
    int d  = tid & 63;       // output dim
    int node = blockIdx.x * 4 + ln;

    if (node < N_NODES) {
        float c   = cnt[node];
        float inv = 1.0f / fmaxf(c, 1.0f);
        mean_s[ln][d] = sum[(long long)node * D + d] * inv;
        x_s[ln][d]    = xin[(long long)node * D + d];
    }
    __syncthreads();

    if (node < N_NODES) {
        float acc = bias[d];
#pragma unroll
        for (int k = 0; k < D; ++k) {
            acc += mean_s[ln][k] * wl_t[k * 65 + d]
                 + x_s[ln][k]    * wr_t[k * 65 + d];
        }
        if (apply_relu) acc = fmaxf(acc, 0.0f);
        out[(long long)node * D + d] = acc;
    }
}

// ---------------------------------------------------------------------------
// Launch
// ---------------------------------------------------------------------------
extern "C" void kernel_launch(void* const* d_in, const int* in_sizes, int n_in,
                              void* d_out, int out_size, void* d_ws, size_t ws_size,
                              hipStream_t stream) {
    const float* x    = (const float*)d_in[0];
    const int*   ei   = (const int*)d_in[1];   // [2, E] row-major: src = ei, dst = ei+E
    const float* w_l1 = (const float*)d_in[2];
    const float* b_l1 = (const float*)d_in[3];
    const float* w_r1 = (const float*)d_in[4];
    const float* w_l2 = (const float*)d_in[5];
    const float* b_l2 = (const float*)d_in[6];
    const float* w_r2 = (const float*)d_in[7];
    float* out = (float*)d_out;

    const int* src = ei;
    const int* dst = ei + N_EDGES;

    // Workspace layout: sum [N*D] | cnt [N] | h [N*D]
    float* sum = (float*)d_ws;
    float* cnt = sum + (size_t)N_NODES * D;
    float* h   = cnt + N_NODES;

    // Zero sum + cnt (ws is poisoned 0xAA before every timed launch)
    hipMemsetAsync(sum, 0, ((size_t)N_NODES * D + N_NODES) * sizeof(float), stream);

    dim3 blk(256);
    // Degree counts (shared by both layers)
    count_kernel<<<dim3((N_EDGES + 255) / 256), blk, 0, stream>>>(dst, cnt);

    // ---- Layer 1 ----
    {
        long long tot = (long long)N_EDGES * D;
        scatter_kernel<<<dim3((unsigned)((tot + 255) / 256)), blk, 0, stream>>>(src, dst, x, sum);
        layer_kernel<<<dim3((N_NODES + 3) / 4), blk, 0, stream>>>(
            sum, cnt, x, w_l1, b_l1, w_r1, h, /*relu=*/1);
    }

    // ---- Layer 2 ----
    {
        hipMemsetAsync(sum, 0, (size_t)N_NODES * D * sizeof(float), stream);
        long long tot = (long long)N_EDGES * D;
        scatter_kernel<<<dim3((unsigned)((tot + 255) / 256)), blk, 0, stream>>>(src, dst, h, sum);
        layer_kernel<<<dim3((N_NODES + 3) / 4), blk, 0, stream>>>(
            sum, cnt, h, w_l2, b_l2, w_r2, out, /*relu=*/0);
    }
}

// Round 2
// 498.126 us; speedup vs baseline: 2.1523x; 2.1523x over previous
//
#include <hip/hip_runtime.h>

#define N_NODES 100000
#define N_EDGES 1600000
#define D 64
#define SCAN_BLK 1024
#define N_SCAN_BLKS ((N_NODES + SCAN_BLK - 1) / SCAN_BLK)   // 98
#define WAVES_PER_BLOCK 8

// ---------------------------------------------------------------------------
// 1) Degree histogram: deg[dst[e]] += 1 (int atomics)
// ---------------------------------------------------------------------------
__global__ __launch_bounds__(256) void degree_kernel(const int* __restrict__ dst,
                                                     int* __restrict__ deg) {
    int e = blockIdx.x * blockDim.x + threadIdx.x;
    if (e < N_EDGES) atomicAdd(&deg[dst[e]], 1);
}

// ---------------------------------------------------------------------------
// 2a) Per-block exclusive scan of deg (Hillis-Steele in LDS), block sums out
// ---------------------------------------------------------------------------
__global__ __launch_bounds__(SCAN_BLK) void scan_blocks(const int* __restrict__ deg,
                                                        int* __restrict__ ex,
                                                        int* __restrict__ blk_sum) {
    __shared__ int tmp[SCAN_BLK];
    int i = blockIdx.x * SCAN_BLK + threadIdx.x;
    int v = (i < N_NODES) ? deg[i] : 0;
    int val = v;
    tmp[threadIdx.x] = val;
    __syncthreads();
    for (int off = 1; off < SCAN_BLK; off <<= 1) {
        int t = (threadIdx.x >= off) ? tmp[threadIdx.x - off] : 0;
        __syncthreads();
        val += t;
        tmp[threadIdx.x] = val;
        __syncthreads();
    }
    if (i < N_NODES) ex[i] = val - v;          // exclusive = inclusive - self
    if (threadIdx.x == SCAN_BLK - 1) blk_sum[blockIdx.x] = val;
}

// 2b) Serial exclusive scan of the 98 block sums (trivial size)
__global__ void scan_partials(const int* __restrict__ blk_sum,
                              int* __restrict__ blk_off) {
    if (threadIdx.x == 0 && blockIdx.x == 0) {
        int run = 0;
        for (int b = 0; b < N_SCAN_BLKS; ++b) { blk_off[b] = run; run += blk_sum[b]; }
    }
}

// 2c) row_ptr[i] = ex[i] + blk_off[i/1024]; cursor = copy; row_ptr[N] = E
__global__ __launch_bounds__(256) void finalize_rowptr(const int* __restrict__ ex,
                                                       const int* __restrict__ blk_off,
                                                       int* __restrict__ row_ptr,
                                                       int* __restrict__ cursor) {
    int i = blockIdx.x * blockDim.x + threadIdx.x;
    if (i < N_NODES) {
        int v = ex[i] + blk_off[i >> 10];
        row_ptr[i] = v;
        cursor[i]  = v;
    } else if (i == N_NODES) {
        row_ptr[N_NODES] = N_EDGES;
    }
}

// ---------------------------------------------------------------------------
// 3) Counting-sort fill: sorted_src[cursor[dst[e]]++] = src[e]
// ---------------------------------------------------------------------------
__global__ __launch_bounds__(256) void fill_kernel(const int* __restrict__ src,
                                                   const int* __restrict__ dst,
                                                   int* __restrict__ cursor,
                                                   int* __restrict__ sorted_src) {
    int e = blockIdx.x * blockDim.x + threadIdx.x;
    if (e < N_EDGES) {
        int p = atomicAdd(&cursor[dst[e]], 1);
        sorted_src[p] = src[e];
    }
}

// ---------------------------------------------------------------------------
// 4) Fused SAGE layer (gather version, no atomics):
//    out[i] = [relu]( mean_{j in N(i)} feat[j] @ w_l^T + b_l + feat[i] @ w_r^T )
//    One 64-lane wave per node; lane = feature dim. Neighbor rows are 256 B
//    coalesced reads from the cache-resident feature table. Weights staged
//    transposed in LDS (stride 65: lanes read consecutive addrs = free 2-way).
// ---------------------------------------------------------------------------
__global__ __launch_bounds__(WAVES_PER_BLOCK * 64) void sage_layer(
    const int* __restrict__ row_ptr, const int* __restrict__ nbr,
    const float* __restrict__ feat,
    const float* __restrict__ w_l, const float* __restrict__ b_l,
    const float* __restrict__ w_r,
    float* __restrict__ out, int apply_relu)
{
    __shared__ float wl_t[D * 65];
    __shared__ float wr_t[D * 65];
    __shared__ float bias[D];
    __shared__ float mean_s[WAVES_PER_BLOCK][D];
    __shared__ float x_s[WAVES_PER_BLOCK][D];

    int tid = threadIdx.x;
    for (int i = tid; i < D * D; i += WAVES_PER_BLOCK * 64) {
        int o = i >> 6, k = i & 63;
        wl_t[k * 65 + o] = w_l[i];
        wr_t[k * 65 + o] = w_r[i];
    }
    if (tid < D) bias[tid] = b_l[tid];
    __syncthreads();

    int wave = tid >> 6;
    int lane = tid & 63;
    int node = blockIdx.x * WAVES_PER_BLOCK + wave;
    if (node >= N_NODES) return;

    int begin = row_ptr[node];
    int end   = row_ptr[node + 1];

    // Neighbor accumulation: chunk of <=64 neighbor ids loaded coalesced,
    // broadcast via shfl; 4-way unroll for memory-level parallelism.
    float acc = 0.0f;
    for (int base = begin; base < end; base += 64) {
        int m = end - base; if (m > 64) m = 64;
        int idx = (lane < m) ? nbr[base + lane] : 0;
        int j = 0;
        for (; j + 4 <= m; j += 4) {
            int s0 = __shfl(idx, j, 64);
            int s1 = __shfl(idx, j + 1, 64);
            int s2 = __shfl(idx, j + 2, 64);
            int s3 = __shfl(idx, j + 3, 64);
            float v0 = feat[(size_t)s0 * D + lane];
            float v1 = feat[(size_t)s1 * D + lane];
            float v2 = feat[(size_t)s2 * D + lane];
            float v3 = feat[(size_t)s3 * D + lane];
            acc += (v0 + v1) + (v2 + v3);
        }
        for (; j < m; ++j) {
            int s = __shfl(idx, j, 64);
            acc += feat[(size_t)s * D + lane];
        }
    }

    int   deg = end - begin;
    float inv = 1.0f / fmaxf((float)deg, 1.0f);
    mean_s[wave][lane] = acc * inv;
    x_s[wave][lane]    = feat[(size_t)node * D + lane];
    // Wave-local LDS write->read: compiler orders via lgkmcnt, no barrier needed.

    float o = bias[lane];
#pragma unroll
    for (int k = 0; k < D; ++k) {
        o += mean_s[wave][k] * wl_t[k * 65 + lane]
           + x_s[wave][k]    * wr_t[k * 65 + lane];
    }
    if (apply_relu) o = fmaxf(o, 0.0f);
    out[(size_t)node * D + lane] = o;
}

// ---------------------------------------------------------------------------
// Launch
// ---------------------------------------------------------------------------
extern "C" void kernel_launch(void* const* d_in, const int* in_sizes, int n_in,
                              void* d_out, int out_size, void* d_ws, size_t ws_size,
                              hipStream_t stream) {
    const float* x    = (const float*)d_in[0];
    const int*   ei   = (const int*)d_in[1];   // [2, E]: src = ei, dst = ei + E
    const float* w_l1 = (const float*)d_in[2];
    const float* b_l1 = (const float*)d_in[3];
    const float* w_r1 = (const float*)d_in[4];
    const float* w_l2 = (const float*)d_in[5];
    const float* b_l2 = (const float*)d_in[6];
    const float* w_r2 = (const float*)d_in[7];
    float* out = (float*)d_out;

    const int* src = ei;
    const int* dst = ei + N_EDGES;

    // Workspace layout (ints then floats):
    int* deg        = (int*)d_ws;                    // N
    int* ex         = deg + N_NODES;                 // N
    int* blk_sum    = ex + N_NODES;                  // 128
    int* blk_off    = blk_sum + 128;                 // 128
    int* row_ptr    = blk_off + 128;                 // N + 1
    int* cursor     = row_ptr + (N_NODES + 1);       // N
    int* sorted_src = cursor + N_NODES;              // E
    float* h        = (float*)(sorted_src + N_EDGES);// N * D

    hipMemsetAsync(deg, 0, (size_t)N_NODES * sizeof(int), stream);

    dim3 blk(256);
    degree_kernel<<<dim3((N_EDGES + 255) / 256), blk, 0, stream>>>(dst, deg);
    scan_blocks<<<dim3(N_SCAN_BLKS), dim3(SCAN_BLK), 0, stream>>>(deg, ex, blk_sum);
    scan_partials<<<dim3(1), dim3(64), 0, stream>>>(blk_sum, blk_off);
    finalize_rowptr<<<dim3((N_NODES + 1 + 255) / 256), blk, 0, stream>>>(ex, blk_off, row_ptr, cursor);
    fill_kernel<<<dim3((N_EDGES + 255) / 256), blk, 0, stream>>>(src, dst, cursor, sorted_src);

    dim3 lblk(WAVES_PER_BLOCK * 64);
    dim3 lgrid((N_NODES + WAVES_PER_BLOCK - 1) / WAVES_PER_BLOCK);
    sage_layer<<<lgrid, lblk, 0, stream>>>(row_ptr, sorted_src, x, w_l1, b_l1, w_r1, h, 1);
    sage_layer<<<lgrid, lblk, 0, stream>>>(row_ptr, sorted_src, h, w_l2, b_l2, w_r2, out, 0);
}